// Round 1
// baseline (209.693 us; speedup 1.0000x reference)
//
#include <hip/hip_runtime.h>
#include <cstdint>
#include <cstddef>

typedef __bf16 bf16;
typedef __bf16 bf16x8 __attribute__((ext_vector_type(8)));
typedef float  f32x4  __attribute__((ext_vector_type(4)));

// ---------------- convert f32 -> bf16 (n multiple of 8) ----------------
__global__ void k_f32_to_bf16(const float* __restrict__ in, bf16* __restrict__ out, int n) {
  int i = (blockIdx.x * blockDim.x + threadIdx.x) * 8;
  if (i >= n) return;
  float4 a = *(const float4*)(in + i);
  float4 b = *(const float4*)(in + i + 4);
  bf16x8 o;
  o[0] = (bf16)a.x; o[1] = (bf16)a.y; o[2] = (bf16)a.z; o[3] = (bf16)a.w;
  o[4] = (bf16)b.x; o[5] = (bf16)b.y; o[6] = (bf16)b.z; o[7] = (bf16)b.w;
  *(bf16x8*)(out + i) = o;
}

// ---------------- transpose f32[R][C] -> bf16[C][R] ----------------
__global__ void k_transpose_f32_bf16(const float* __restrict__ in, bf16* __restrict__ out,
                                     int R, int C) {
  __shared__ float tile[32][33];
  int c0 = blockIdx.x * 32, r0 = blockIdx.y * 32;
  int tx = threadIdx.x & 31, ty = threadIdx.x >> 5;  // 32 x 8
#pragma unroll
  for (int i = 0; i < 32; i += 8)
    tile[ty + i][tx] = in[(size_t)(r0 + ty + i) * C + c0 + tx];
  __syncthreads();
#pragma unroll
  for (int i = 0; i < 32; i += 8)
    out[(size_t)(c0 + ty + i) * R + r0 + tx] = (bf16)tile[tx][ty + i];
}

// ---------------- RoPE tables: cos/sin [T][32] fp32 ----------------
__global__ void k_rope_tables(float* __restrict__ cosT, float* __restrict__ sinT, int total) {
  int i = blockIdx.x * blockDim.x + threadIdx.x;
  if (i >= total) return;
  int t = i >> 5, j = i & 31;
  float inv = powf(10000.0f, -(float)j * (1.0f / 32.0f));
  float f = (float)t * inv;
  cosT[i] = cosf(f);
  sinT[i] = sinf(f);
}

// ---------------- RoPE q,k: qkv[4096][3072] -> qr,kr [B][H][T][64] ----------------
__global__ void k_rope_qk(const bf16* __restrict__ qkv, const float* __restrict__ cosT,
                          const float* __restrict__ sinT, bf16* __restrict__ qr,
                          bf16* __restrict__ kr) {
  int i = blockIdx.x * blockDim.x + threadIdx.x;  // B*T*H*32 = 2^21
  int j = i & 31;
  int h = (i >> 5) & 15;
  int t = (i >> 9) & 2047;
  int b = i >> 20;
  size_t base = (size_t)(b * 2048 + t) * 3072;
  float c = cosT[t * 32 + j], s = sinT[t * 32 + j];
  float qlo = (float)qkv[base + h * 64 + j];
  float qhi = (float)qkv[base + h * 64 + j + 32];
  float klo = (float)qkv[base + 1024 + h * 64 + j];
  float khi = (float)qkv[base + 1024 + h * 64 + j + 32];
  size_t ob = ((size_t)(b * 16 + h) * 2048 + t) * 64;
  qr[ob + j]      = (bf16)(qlo * c - qhi * s);
  qr[ob + j + 32] = (bf16)(qhi * c + qlo * s);
  kr[ob + j]      = (bf16)(klo * c - khi * s);
  kr[ob + j + 32] = (bf16)(khi * c + klo * s);
}

// ---------------- V scatter: qkv v-section -> vt [B][H][64][T] ----------------
__global__ void k_v_scatter(const bf16* __restrict__ qkv, bf16* __restrict__ vt) {
  __shared__ bf16 tile[64][66];
  int bh = blockIdx.y;           // 0..31
  int t0 = blockIdx.x * 64;
  int b = bh >> 4, h = bh & 15;
  int tt = threadIdx.x >> 2, c4 = (threadIdx.x & 3) * 16;
  const bf16* src = qkv + (size_t)(b * 2048 + t0 + tt) * 3072 + 2048 + h * 64 + c4;
  bf16x8 v0 = *(const bf16x8*)src;
  bf16x8 v1 = *(const bf16x8*)(src + 8);
#pragma unroll
  for (int j = 0; j < 8; j++) { tile[tt][c4 + j] = v0[j]; tile[tt][c4 + 8 + j] = v1[j]; }
  __syncthreads();
  int d = threadIdx.x >> 2, tc0 = (threadIdx.x & 3) * 16;
  bf16x8 o0, o1;
#pragma unroll
  for (int j = 0; j < 8; j++) { o0[j] = tile[tc0 + j][d]; o1[j] = tile[tc0 + 8 + j][d]; }
  bf16* dst = vt + ((size_t)bh * 64 + d) * 2048 + t0 + tc0;
  *(bf16x8*)dst = o0;
  *(bf16x8*)(dst + 8) = o1;
}

// ---------------- GEMM: C[M][N] = A[M][K] * Bt[N][K]^T  (bf16 in, f32 acc) ----------------
template <int OUTF32>
__global__ __launch_bounds__(256) void k_gemm_bt(const bf16* __restrict__ A,
                                                 const bf16* __restrict__ Bt,
                                                 float* __restrict__ Cf, bf16* __restrict__ Cb,
                                                 int M, int N, int K) {
  __shared__ __align__(16) bf16 sA[128][48];
  __shared__ __align__(16) bf16 sB[128][48];
  int m0 = blockIdx.y * 128, n0 = blockIdx.x * 128;
  int t = threadIdx.x, lane = t & 63, w = t >> 6;
  int wr = w >> 1, wc = w & 1;
  int lr = lane & 15, q2 = lane >> 4, lk = q2 * 8;
  int srow = t >> 1, sc = (t & 1) * 16;
  f32x4 acc[4][4] = {};
  for (int k0 = 0; k0 < K; k0 += 32) {
    const bf16* ga = A + (size_t)(m0 + srow) * K + k0 + sc;
    const bf16* gb = Bt + (size_t)(n0 + srow) * K + k0 + sc;
    bf16x8 a0 = *(const bf16x8*)ga, a1 = *(const bf16x8*)(ga + 8);
    bf16x8 b0 = *(const bf16x8*)gb, b1 = *(const bf16x8*)(gb + 8);
    __syncthreads();
    *(bf16x8*)&sA[srow][sc] = a0; *(bf16x8*)&sA[srow][sc + 8] = a1;
    *(bf16x8*)&sB[srow][sc] = b0; *(bf16x8*)&sB[srow][sc + 8] = b1;
    __syncthreads();
    bf16x8 af[4], bfr[4];
#pragma unroll
    for (int i = 0; i < 4; i++) af[i]  = *(const bf16x8*)&sA[wr * 64 + i * 16 + lr][lk];
#pragma unroll
    for (int i = 0; i < 4; i++) bfr[i] = *(const bf16x8*)&sB[wc * 64 + i * 16 + lr][lk];
#pragma unroll
    for (int mi = 0; mi < 4; mi++)
#pragma unroll
      for (int ni = 0; ni < 4; ni++)
        acc[mi][ni] = __builtin_amdgcn_mfma_f32_16x16x32_bf16(af[mi], bfr[ni], acc[mi][ni], 0, 0, 0);
  }
  int row_base = m0 + wr * 64, col_base = n0 + wc * 64;
#pragma unroll
  for (int mi = 0; mi < 4; mi++)
#pragma unroll
    for (int ni = 0; ni < 4; ni++) {
      int col = col_base + ni * 16 + lr;
#pragma unroll
      for (int r = 0; r < 4; r++) {
        int row = row_base + mi * 16 + q2 * 4 + r;
        float v = acc[mi][ni][r];
        if (OUTF32) Cf[(size_t)row * N + col] = v;
        else        Cb[(size_t)row * N + col] = (bf16)v;
      }
    }
}

// ---------------- causal flash attention ----------------
// qr,kr: [BH][T][64]; vt: [BH][64][T]; out: [B][T][1024] bf16
__global__ __launch_bounds__(256) void k_flash(const bf16* __restrict__ qr,
                                               const bf16* __restrict__ kr,
                                               const bf16* __restrict__ vt,
                                               bf16* __restrict__ out) {
  const int T = 2048;
  int qt = blockIdx.x;   // 0..31 (q tile of 64)
  int bh = blockIdx.y;   // 0..31
  int b = bh >> 4, h = bh & 15;
  __shared__ __align__(16) bf16 sK[64][72];
  __shared__ __align__(16) bf16 sV[64][72];   // sV[d][kk]
  __shared__ __align__(16) bf16 sP[64][72];
  int t = threadIdx.x, lane = t & 63, w = t >> 6;
  int lr = lane & 15, q2 = lane >> 4, lk = q2 * 8;
  int srow = t >> 2, sc = (t & 3) * 16;
  const bf16* qbase = qr + ((size_t)bh * T + qt * 64 + w * 16 + lr) * 64;
  bf16x8 qf0 = *(const bf16x8*)(qbase + lk);
  bf16x8 qf1 = *(const bf16x8*)(qbase + 32 + lk);
  f32x4 o[4] = {};
  float m[4], l[4];
#pragma unroll
  for (int r = 0; r < 4; r++) { m[r] = -1e30f; l[r] = 0.f; }
  const float scale = 0.125f;
  for (int kt = 0; kt <= qt; kt++) {
    const bf16* gk = kr + ((size_t)bh * T + kt * 64 + srow) * 64 + sc;
    const bf16* gv = vt + ((size_t)bh * 64 + srow) * T + kt * 64 + sc;
    bf16x8 kv0 = *(const bf16x8*)gk, kv1 = *(const bf16x8*)(gk + 8);
    bf16x8 vv0 = *(const bf16x8*)gv, vv1 = *(const bf16x8*)(gv + 8);
    __syncthreads();
    *(bf16x8*)&sK[srow][sc] = kv0; *(bf16x8*)&sK[srow][sc + 8] = kv1;
    *(bf16x8*)&sV[srow][sc] = vv0; *(bf16x8*)&sV[srow][sc + 8] = vv1;
    __syncthreads();
    // ---- S = Q K^T ----
    f32x4 s[4];
#pragma unroll
    for (int kb = 0; kb < 4; kb++) {
      f32x4 acc = {};
      bf16x8 kf0 = *(const bf16x8*)&sK[kb * 16 + lr][lk];
      bf16x8 kf1 = *(const bf16x8*)&sK[kb * 16 + lr][32 + lk];
      acc = __builtin_amdgcn_mfma_f32_16x16x32_bf16(qf0, kf0, acc, 0, 0, 0);
      acc = __builtin_amdgcn_mfma_f32_16x16x32_bf16(qf1, kf1, acc, 0, 0, 0);
      s[kb] = acc;
    }
    bool diag = (kt == qt);
#pragma unroll
    for (int kb = 0; kb < 4; kb++)
#pragma unroll
      for (int r = 0; r < 4; r++) {
        float sv = s[kb][r] * scale;
        if (diag && (kb * 16 + lr) > (w * 16 + q2 * 4 + r)) sv = -1e30f;
        s[kb][r] = sv;
      }
    // ---- online softmax ----
    float alpha[4];
#pragma unroll
    for (int r = 0; r < 4; r++) {
      float v = fmaxf(fmaxf(s[0][r], s[1][r]), fmaxf(s[2][r], s[3][r]));
#pragma unroll
      for (int off = 1; off < 16; off <<= 1) v = fmaxf(v, __shfl_xor(v, off, 64));
      float mn = fmaxf(m[r], v);
      alpha[r] = __expf(m[r] - mn);
      m[r] = mn;
    }
    float rs[4] = {0.f, 0.f, 0.f, 0.f};
#pragma unroll
    for (int kb = 0; kb < 4; kb++)
#pragma unroll
      for (int r = 0; r < 4; r++) {
        float p = __expf(s[kb][r] - m[r]);
        s[kb][r] = p;
        rs[r] += p;
      }
#pragma unroll
    for (int r = 0; r < 4; r++) {
#pragma unroll
      for (int off = 1; off < 16; off <<= 1) rs[r] += __shfl_xor(rs[r], off, 64);
      l[r] = l[r] * alpha[r] + rs[r];
    }
#pragma unroll
    for (int db = 0; db < 4; db++)
#pragma unroll
      for (int r = 0; r < 4; r++) o[db][r] *= alpha[r];
    // ---- P -> LDS (per-wave rows, no barrier needed) ----
#pragma unroll
    for (int kb = 0; kb < 4; kb++)
#pragma unroll
      for (int r = 0; r < 4; r++)
        sP[w * 16 + q2 * 4 + r][kb * 16 + lr] = (bf16)s[kb][r];
    // ---- O += P V ----
#pragma unroll
    for (int kh = 0; kh < 2; kh++) {
      bf16x8 pa = *(const bf16x8*)&sP[w * 16 + lr][kh * 32 + lk];
#pragma unroll
      for (int db = 0; db < 4; db++) {
        bf16x8 vb = *(const bf16x8*)&sV[db * 16 + lr][kh * 32 + lk];
        o[db] = __builtin_amdgcn_mfma_f32_16x16x32_bf16(pa, vb, o[db], 0, 0, 0);
      }
    }
  }
  // ---- write out [B][T][C] ----
#pragma unroll
  for (int db = 0; db < 4; db++)
#pragma unroll
    for (int r = 0; r < 4; r++) {
      int q = qt * 64 + w * 16 + q2 * 4 + r;
      float val = o[db][r] / l[r];
      out[((size_t)b * T + q) * 1024 + h * 64 + db * 16 + lr] = (bf16)val;
    }
}

// ---------------- launch ----------------
extern "C" void kernel_launch(void* const* d_in, const int* in_sizes, int n_in,
                              void* d_out, int out_size, void* d_ws, size_t ws_size,
                              hipStream_t stream) {
  const float* x     = (const float*)d_in[0];
  const float* Wqkv  = (const float*)d_in[1];
  const float* Wproj = (const float*)d_in[2];
  float* outp = (float*)d_out;
  const int B = 2, T = 2048, C = 1024;
  const int M = B * T;  // 4096

  char* ws = (char*)d_ws;
  size_t off = 0;
  auto alloc = [&](size_t bytes) {
    void* p = ws + off;
    off += (bytes + 255) & ~(size_t)255;
    return p;
  };
  bf16* xb     = (bf16*)alloc((size_t)M * C * 2);        // 8 MB
  bf16* wqkvt  = (bf16*)alloc((size_t)3 * C * C * 2);    // 6 MB
  bf16* wprojt = (bf16*)alloc((size_t)C * C * 2);        // 2 MB
  float* cosT  = (float*)alloc((size_t)T * 32 * 4);
  float* sinT  = (float*)alloc((size_t)T * 32 * 4);
  bf16* qkv    = (bf16*)alloc((size_t)M * 3 * C * 2);    // 24 MB
  bf16* qr     = (bf16*)alloc((size_t)M * C * 2);        // 8 MB
  bf16* kr     = (bf16*)alloc((size_t)M * C * 2);        // 8 MB
  bf16* vt     = (bf16*)alloc((size_t)M * C * 2);        // 8 MB
  bf16* attn   = qkv;  // alias: qkv dead after rope/v_scatter
  // total ~64.5 MiB of d_ws

  k_f32_to_bf16<<<dim3(M * C / 8 / 256), dim3(256), 0, stream>>>(x, xb, M * C);
  k_transpose_f32_bf16<<<dim3(3 * C / 32, C / 32), dim3(256), 0, stream>>>(Wqkv, wqkvt, C, 3 * C);
  k_transpose_f32_bf16<<<dim3(C / 32, C / 32), dim3(256), 0, stream>>>(Wproj, wprojt, C, C);
  k_rope_tables<<<dim3(T * 32 / 256), dim3(256), 0, stream>>>(cosT, sinT, T * 32);
  // qkv = xb @ wqkvt^T : M=4096, N=3072, K=1024
  k_gemm_bt<0><<<dim3(3 * C / 128, M / 128), dim3(256), 0, stream>>>(xb, wqkvt, (float*)nullptr, qkv, M, 3 * C, C);
  k_rope_qk<<<dim3((B * T * 16 * 32) / 256), dim3(256), 0, stream>>>(qkv, cosT, sinT, qr, kr);
  k_v_scatter<<<dim3(T / 64, 32), dim3(256), 0, stream>>>(qkv, vt);
  k_flash<<<dim3(T / 64, 32), dim3(256), 0, stream>>>(qr, kr, vt, attn);
  // out = attn @ wprojt^T : M=4096, N=1024, K=1024, fp32 out
  k_gemm_bt<1><<<dim3(C / 128, M / 128), dim3(256), 0, stream>>>(attn, wprojt, outp, (bf16*)nullptr, M, C, C);
}

// Round 2
// 138.663 us; speedup vs baseline: 1.5123x; 1.5123x over previous
//
#include <hip/hip_runtime.h>
#include <cstdint>
#include <cstddef>

typedef __bf16 bf16;
typedef __bf16 bf16x2 __attribute__((ext_vector_type(2)));
typedef __bf16 bf16x8 __attribute__((ext_vector_type(8)));
typedef float  f32x4  __attribute__((ext_vector_type(4)));

// global -> LDS direct (16B/lane, dest = wave-uniform base + lane*16)
#define G2L(src, dst)                                                          \
  __builtin_amdgcn_global_load_lds(                                            \
      (const __attribute__((address_space(1))) unsigned int*)(src),            \
      (__attribute__((address_space(3))) unsigned int*)(dst), 16, 0, 0)

// ---------------- convert f32 -> bf16 (n multiple of 8) ----------------
__global__ void k_f32_to_bf16(const float* __restrict__ in, bf16* __restrict__ out, int n) {
  int i = (blockIdx.x * blockDim.x + threadIdx.x) * 8;
  if (i >= n) return;
  float4 a = *(const float4*)(in + i);
  float4 b = *(const float4*)(in + i + 4);
  bf16x8 o;
  o[0] = (bf16)a.x; o[1] = (bf16)a.y; o[2] = (bf16)a.z; o[3] = (bf16)a.w;
  o[4] = (bf16)b.x; o[5] = (bf16)b.y; o[6] = (bf16)b.z; o[7] = (bf16)b.w;
  *(bf16x8*)(out + i) = o;
}

// ---------------- transpose f32[R][C] -> bf16[C][R] ----------------
__global__ void k_transpose_f32_bf16(const float* __restrict__ in, bf16* __restrict__ out,
                                     int R, int C) {
  __shared__ float tile[32][33];
  int c0 = blockIdx.x * 32, r0 = blockIdx.y * 32;
  int tx = threadIdx.x & 31, ty = threadIdx.x >> 5;  // 32 x 8
#pragma unroll
  for (int i = 0; i < 32; i += 8)
    tile[ty + i][tx] = in[(size_t)(r0 + ty + i) * C + c0 + tx];
  __syncthreads();
#pragma unroll
  for (int i = 0; i < 32; i += 8)
    out[(size_t)(c0 + ty + i) * R + r0 + tx] = (bf16)tile[tx][ty + i];
}

// ---------------- RoPE tables: cos/sin [T][32] fp32 ----------------
__global__ void k_rope_tables(float* __restrict__ cosT, float* __restrict__ sinT, int total) {
  int i = blockIdx.x * blockDim.x + threadIdx.x;
  if (i >= total) return;
  int t = i >> 5, j = i & 31;
  float inv = powf(10000.0f, -(float)j * (1.0f / 32.0f));
  float f = (float)t * inv;
  cosT[i] = cosf(f);
  sinT[i] = sinf(f);
}

// ---------------- RoPE q,k: qkv[4096][3072] -> qr,kr [B][H][T][64] ----------------
// q is pre-scaled by 0.125 (exact pow2 in bf16) so flash needs no scale.
__global__ void k_rope_qk(const bf16* __restrict__ qkv, const float* __restrict__ cosT,
                          const float* __restrict__ sinT, bf16* __restrict__ qr,
                          bf16* __restrict__ kr) {
  int i = blockIdx.x * blockDim.x + threadIdx.x;  // B*T*H*32 = 2^21
  int j = i & 31;
  int h = (i >> 5) & 15;
  int t = (i >> 9) & 2047;
  int b = i >> 20;
  size_t base = (size_t)(b * 2048 + t) * 3072;
  float c = cosT[t * 32 + j], s = sinT[t * 32 + j];
  float qlo = (float)qkv[base + h * 64 + j];
  float qhi = (float)qkv[base + h * 64 + j + 32];
  float klo = (float)qkv[base + 1024 + h * 64 + j];
  float khi = (float)qkv[base + 1024 + h * 64 + j + 32];
  size_t ob = ((size_t)(b * 16 + h) * 2048 + t) * 64;
  qr[ob + j]      = (bf16)((qlo * c - qhi * s) * 0.125f);
  qr[ob + j + 32] = (bf16)((qhi * c + qlo * s) * 0.125f);
  kr[ob + j]      = (bf16)(klo * c - khi * s);
  kr[ob + j + 32] = (bf16)(khi * c + klo * s);
}

// ---------------- V scatter: qkv v-section -> vt [B][H][64][T] ----------------
__global__ void k_v_scatter(const bf16* __restrict__ qkv, bf16* __restrict__ vt) {
  __shared__ bf16 tile[64][66];
  int bh = blockIdx.y;           // 0..31
  int t0 = blockIdx.x * 64;
  int b = bh >> 4, h = bh & 15;
  int tt = threadIdx.x >> 2, c4 = (threadIdx.x & 3) * 16;
  const bf16* src = qkv + (size_t)(b * 2048 + t0 + tt) * 3072 + 2048 + h * 64 + c4;
  bf16x8 v0 = *(const bf16x8*)src;
  bf16x8 v1 = *(const bf16x8*)(src + 8);
#pragma unroll
  for (int j = 0; j < 8; j++) { tile[tt][c4 + j] = v0[j]; tile[tt][c4 + 8 + j] = v1[j]; }
  __syncthreads();
  int d = threadIdx.x >> 2, tc0 = (threadIdx.x & 3) * 16;
  bf16x8 o0, o1;
#pragma unroll
  for (int j = 0; j < 8; j++) { o0[j] = tile[tc0 + j][d]; o1[j] = tile[tc0 + 8 + j][d]; }
  bf16* dst = vt + ((size_t)bh * 64 + d) * 2048 + t0 + tc0;
  *(bf16x8*)dst = o0;
  *(bf16x8*)(dst + 8) = o1;
}

// ---------------- GEMM (m97 structure): C[M][N] = A[M][K] * Bt[N][K]^T ----------------
// 128x128 tile, BK=64, global_load_lds staging, linear LDS + XOR chunk swizzle.
template <int OUTF32>
__global__ __launch_bounds__(256) void k_gemm_bt(const bf16* __restrict__ A,
                                                 const bf16* __restrict__ Bt,
                                                 float* __restrict__ Cf, bf16* __restrict__ Cb,
                                                 int M, int N, int K) {
  __shared__ __align__(16) bf16 sA[128 * 64];
  __shared__ __align__(16) bf16 sB[128 * 64];
  int m0 = blockIdx.y * 128, n0 = blockIdx.x * 128;
  int t = threadIdx.x, lane = t & 63, w = t >> 6;
  int wr = w >> 1, wc = w & 1;
  int lr = lane & 15, q2 = lane >> 4;
  int srow8 = lane >> 3, pc8 = lane & 7;
  f32x4 acc[4][4] = {};
  for (int k0 = 0; k0 < K; k0 += 64) {
#pragma unroll
    for (int is = 0; is < 4; is++) {
      int r = w * 32 + is * 8 + srow8;
      int lc = pc8 ^ (r & 7);
      G2L(A + (size_t)(m0 + r) * K + k0 + lc * 8, &sA[(w * 32 + is * 8) * 64]);
    }
#pragma unroll
    for (int is = 0; is < 4; is++) {
      int r = w * 32 + is * 8 + srow8;
      int lc = pc8 ^ (r & 7);
      G2L(Bt + (size_t)(n0 + r) * K + k0 + lc * 8, &sB[(w * 32 + is * 8) * 64]);
    }
    __syncthreads();   // drains vmcnt -> staged tile visible
#pragma unroll
    for (int ch = 0; ch < 2; ch++) {
      bf16x8 af[4], bfr[4];
#pragma unroll
      for (int i = 0; i < 4; i++) {
        int r = wr * 64 + i * 16 + lr;
        af[i] = *(const bf16x8*)&sA[r * 64 + (((ch * 4 + q2) ^ (r & 7)) * 8)];
      }
#pragma unroll
      for (int i = 0; i < 4; i++) {
        int r = wc * 64 + i * 16 + lr;
        bfr[i] = *(const bf16x8*)&sB[r * 64 + (((ch * 4 + q2) ^ (r & 7)) * 8)];
      }
#pragma unroll
      for (int mi = 0; mi < 4; mi++)
#pragma unroll
        for (int ni = 0; ni < 4; ni++)
          acc[mi][ni] = __builtin_amdgcn_mfma_f32_16x16x32_bf16(af[mi], bfr[ni], acc[mi][ni], 0, 0, 0);
    }
    __syncthreads();   // compute done before next stage overwrites
  }
  int row_base = m0 + wr * 64, col_base = n0 + wc * 64;
#pragma unroll
  for (int mi = 0; mi < 4; mi++)
#pragma unroll
    for (int ni = 0; ni < 4; ni++) {
      int col = col_base + ni * 16 + lr;
#pragma unroll
      for (int r = 0; r < 4; r++) {
        int row = row_base + mi * 16 + q2 * 4 + r;
        float v = acc[mi][ni][r];
        if (OUTF32) Cf[(size_t)row * N + col] = v;
        else        Cb[(size_t)row * N + col] = (bf16)v;
      }
    }
}

// ---------------- causal flash attention (swapped-QK^T, dbuf global_load_lds) ----------------
// qr,kr: [BH][T][64]; vt: [BH][64][T]; out: [B][T][1024] bf16
// Folded schedule: block handles q-tiles {pair, 31-pair} -> 33 kt-iters per block.
__global__ __launch_bounds__(256) void k_flash(const bf16* __restrict__ qr,
                                               const bf16* __restrict__ kr,
                                               const bf16* __restrict__ vt,
                                               bf16* __restrict__ out) {
  const int T = 2048;
  int pair = blockIdx.x;   // 0..15
  int bh = blockIdx.y;     // 0..31
  int b = bh >> 4, h = bh & 15;
  __shared__ __align__(16) bf16 sK[2][64 * 64];
  __shared__ __align__(16) bf16 sV[2][64 * 64];
  __shared__ __align__(16) bf16 sP[64][72];
  int t = threadIdx.x, lane = t & 63, w = t >> 6;
  int lr = lane & 15, q2 = lane >> 4;
  int srow8 = lane >> 3, pc8 = lane & 7;

  const bf16* Kbh = kr + (size_t)bh * T * 64;
  const bf16* Vbh = vt + (size_t)bh * 64 * T;

  for (int sel = 0; sel < 2; sel++) {
    int qt = sel ? 31 - pair : pair;
    int nk = qt + 1;
    // Q fragment: B-operand (col = q = w*16+lr local), pre-scaled by 1/8
    const bf16* qrow = qr + ((size_t)bh * T + qt * 64 + w * 16 + lr) * 64;
    bf16x8 qf0 = *(const bf16x8*)(qrow + q2 * 8);
    bf16x8 qf1 = *(const bf16x8*)(qrow + 32 + q2 * 8);
    f32x4 o[4] = {};
    float m = -1e30f, l = 0.f;

    auto stage = [&](int buf, int kt) {
#pragma unroll
      for (int is = 0; is < 2; is++) {
        int r = w * 16 + is * 8 + srow8;
        int lc = pc8 ^ (r & 7);
        G2L(Kbh + (size_t)(kt * 64 + r) * 64 + lc * 8, &sK[buf][(w * 16 + is * 8) * 64]);
      }
#pragma unroll
      for (int is = 0; is < 2; is++) {
        int d = w * 16 + is * 8 + srow8;
        int lc = pc8 ^ (d & 7);
        G2L(Vbh + (size_t)d * T + kt * 64 + lc * 8, &sV[buf][(w * 16 + is * 8) * 64]);
      }
    };

    stage(0, 0);
    for (int kt = 0; kt < nk; kt++) {
      int buf = kt & 1;
      if (kt + 1 < nk) {
        stage(buf ^ 1, kt + 1);
        asm volatile("s_waitcnt vmcnt(4)" ::: "memory");  // this tile's 4 loads done; next stays in flight
      } else {
        asm volatile("s_waitcnt vmcnt(0)" ::: "memory");
      }
      __builtin_amdgcn_s_barrier();
      asm volatile("" ::: "memory");
      __builtin_amdgcn_sched_barrier(0);
      const bf16* Kb = &sK[buf][0];
      const bf16* Vb = &sV[buf][0];
      // ---- S^T = K Q^T : row = k-local, col = q-local ----
      f32x4 s[4];
#pragma unroll
      for (int kb = 0; kb < 4; kb++) {
        int rr = kb * 16 + lr;
        bf16x8 kf0 = *(const bf16x8*)&Kb[rr * 64 + ((q2 ^ (lr & 7)) * 8)];
        bf16x8 kf1 = *(const bf16x8*)&Kb[rr * 64 + (((4 + q2) ^ (lr & 7)) * 8)];
        f32x4 a = {};
        a = __builtin_amdgcn_mfma_f32_16x16x32_bf16(kf0, qf0, a, 0, 0, 0);
        a = __builtin_amdgcn_mfma_f32_16x16x32_bf16(kf1, qf1, a, 0, 0, 0);
        s[kb] = a;
      }
      if (kt == qt) {  // diagonal tile mask: k_local > q_local
#pragma unroll
        for (int kb = 0; kb < 4; kb++)
#pragma unroll
          for (int r = 0; r < 4; r++)
            if (kb * 16 + q2 * 4 + r > w * 16 + lr) s[kb][r] = -1e30f;
      }
      // ---- lane-local online softmax (q = w*16+lr) ----
      float px = -1e30f;
#pragma unroll
      for (int kb = 0; kb < 4; kb++)
#pragma unroll
        for (int r = 0; r < 4; r++) px = fmaxf(px, s[kb][r]);
      px = fmaxf(px, __shfl_xor(px, 16, 64));
      px = fmaxf(px, __shfl_xor(px, 32, 64));
      float mn = fmaxf(m, px);
      float alpha = __expf(m - mn);
      m = mn;
      float rs = 0.f;
#pragma unroll
      for (int kb = 0; kb < 4; kb++)
#pragma unroll
        for (int r = 0; r < 4; r++) {
          float p = __expf(s[kb][r] - m);
          s[kb][r] = p;
          rs += p;
        }
      rs += __shfl_xor(rs, 16, 64);
      rs += __shfl_xor(rs, 32, 64);
      l = l * alpha + rs;
      // ---- P -> per-wave LDS rows (b32 packed writes) ----
#pragma unroll
      for (int kb = 0; kb < 4; kb++) {
        bf16x2 p01; p01[0] = (bf16)s[kb][0]; p01[1] = (bf16)s[kb][1];
        bf16x2 p23; p23[0] = (bf16)s[kb][2]; p23[1] = (bf16)s[kb][3];
        *(bf16x2*)&sP[w * 16 + lr][kb * 16 + q2 * 4]     = p01;
        *(bf16x2*)&sP[w * 16 + lr][kb * 16 + q2 * 4 + 2] = p23;
      }
      // ---- rescale O (alpha redistributed to o's q rows) ----
      float ar[4];
#pragma unroll
      for (int r = 0; r < 4; r++) ar[r] = __shfl(alpha, q2 * 4 + r, 64);
#pragma unroll
      for (int db = 0; db < 4; db++)
#pragma unroll
        for (int r = 0; r < 4; r++) o[db][r] *= ar[r];
      // ---- O += P V ----
#pragma unroll
      for (int kh = 0; kh < 2; kh++) {
        bf16x8 pa = *(const bf16x8*)&sP[w * 16 + lr][kh * 32 + q2 * 8];
#pragma unroll
        for (int db = 0; db < 4; db++) {
          int dd = db * 16 + lr;
          bf16x8 vb = *(const bf16x8*)&Vb[dd * 64 + (((kh * 4 + q2) ^ (lr & 7)) * 8)];
          o[db] = __builtin_amdgcn_mfma_f32_16x16x32_bf16(pa, vb, o[db], 0, 0, 0);
        }
      }
      asm volatile("" ::: "memory");
      __builtin_amdgcn_s_barrier();   // compute done; next stage may overwrite buf^1
      asm volatile("" ::: "memory");
    }
    // ---- epilogue ----
    float linv[4];
#pragma unroll
    for (int r = 0; r < 4; r++) linv[r] = 1.0f / __shfl(l, q2 * 4 + r, 64);
#pragma unroll
    for (int db = 0; db < 4; db++)
#pragma unroll
      for (int r = 0; r < 4; r++) {
        int q = qt * 64 + w * 16 + q2 * 4 + r;
        out[((size_t)b * T + q) * 1024 + h * 64 + db * 16 + lr] = (bf16)(o[db][r] * linv[r]);
      }
  }
}

// ---------------- launch ----------------
extern "C" void kernel_launch(void* const* d_in, const int* in_sizes, int n_in,
                              void* d_out, int out_size, void* d_ws, size_t ws_size,
                              hipStream_t stream) {
  const float* x     = (const float*)d_in[0];
  const float* Wqkv  = (const float*)d_in[1];
  const float* Wproj = (const float*)d_in[2];
  float* outp = (float*)d_out;
  const int B = 2, T = 2048, C = 1024;
  const int M = B * T;  // 4096

  char* ws = (char*)d_ws;
  size_t off = 0;
  auto alloc = [&](size_t bytes) {
    void* p = ws + off;
    off += (bytes + 255) & ~(size_t)255;
    return p;
  };
  bf16* xb     = (bf16*)alloc((size_t)M * C * 2);
  bf16* wqkvt  = (bf16*)alloc((size_t)3 * C * C * 2);
  bf16* wprojt = (bf16*)alloc((size_t)C * C * 2);
  float* cosT  = (float*)alloc((size_t)T * 32 * 4);
  float* sinT  = (float*)alloc((size_t)T * 32 * 4);
  bf16* qkv    = (bf16*)alloc((size_t)M * 3 * C * 2);
  bf16* qr     = (bf16*)alloc((size_t)M * C * 2);
  bf16* kr     = (bf16*)alloc((size_t)M * C * 2);
  bf16* vt     = (bf16*)alloc((size_t)M * C * 2);
  bf16* attn   = qkv;  // alias: qkv dead after rope/v_scatter

  k_f32_to_bf16<<<dim3(M * C / 8 / 256), dim3(256), 0, stream>>>(x, xb, M * C);
  k_transpose_f32_bf16<<<dim3(3 * C / 32, C / 32), dim3(256), 0, stream>>>(Wqkv, wqkvt, C, 3 * C);
  k_transpose_f32_bf16<<<dim3(C / 32, C / 32), dim3(256), 0, stream>>>(Wproj, wprojt, C, C);
  k_rope_tables<<<dim3(T * 32 / 256), dim3(256), 0, stream>>>(cosT, sinT, T * 32);
  k_gemm_bt<0><<<dim3(3 * C / 128, M / 128), dim3(256), 0, stream>>>(xb, wqkvt, (float*)nullptr, qkv, M, 3 * C, C);
  k_rope_qk<<<dim3((B * T * 16 * 32) / 256), dim3(256), 0, stream>>>(qkv, cosT, sinT, qr, kr);
  k_v_scatter<<<dim3(T / 64, 32), dim3(256), 0, stream>>>(qkv, vt);
  k_flash<<<dim3(16, 32), dim3(256), 0, stream>>>(qr, kr, vt, attn);
  k_gemm_bt<1><<<dim3(C / 128, M / 128), dim3(256), 0, stream>>>(attn, wprojt, outp, (bf16*)nullptr, M, C, C);
}